// Round 7
// baseline (170.486 us; speedup 1.0000x reference)
//
#include <hip/hip_runtime.h>
#include <hip/hip_bf16.h>
#include <math.h>

#define BB   4
#define CC   256
#define DQK  32
#define NN   4096
#define QBLK 64
#define KVB  128
#define NQB  (NN / QBLK)
#define SCALE 0.17677669529663687f   // 1/sqrt(32 + 1e-8)

typedef short  bf16x8 __attribute__((ext_vector_type(8)));
typedef float  f32x4  __attribute__((ext_vector_type(4)));
typedef unsigned short u16;

__device__ __forceinline__ u16 f2bf(float f) {
    __hip_bfloat16 h = __float2bfloat16(f);   // round-to-nearest
    return *reinterpret_cast<u16*>(&h);
}

// ---------------------------------------------------------------------------
// Kernel 0: pack W -> bf16 [320][256] (Q rows & bias scaled), bias -> f32[320]
// ---------------------------------------------------------------------------
__global__ __launch_bounds__(256) void wprep_kernel(
    const float* __restrict__ Wq, const float* __restrict__ bq,
    const float* __restrict__ Wk, const float* __restrict__ bk,
    const float* __restrict__ Wv, const float* __restrict__ bv,
    u16* __restrict__ Wb, float* __restrict__ biasb)
{
    const int r = blockIdx.x;
    const int t = threadIdx.x;
    float w, bias;
    if (r < DQK)          { w = Wq[r * CC + t] * SCALE;     bias = bq[r] * SCALE; }
    else if (r < 2 * DQK) { w = Wk[(r - DQK) * CC + t];     bias = bk[r - DQK];  }
    else                  { w = Wv[(r - 2 * DQK) * CC + t]; bias = bv[r - 2 * DQK]; }
    Wb[r * CC + t] = f2bf(w);
    if (t == 0) biasb[r] = bias;
}

// ---------------------------------------------------------------------------
// Kernel 1: transpose x [B][C][N] f32 -> xbf [B][N][C] bf16 (64x64 LDS tiles)
// ---------------------------------------------------------------------------
__global__ __launch_bounds__(256) void xpose_kernel(
    const float* __restrict__ x, u16* __restrict__ xbf)
{
    __shared__ u16 tile[64][65];
    const int b  = blockIdx.z;
    const int n0 = blockIdx.x * 64;
    const int c0 = blockIdx.y * 64;
    const int t  = threadIdx.x;
    const int tl = t & 63;
    const int th = t >> 6;

    #pragma unroll
    for (int rr = 0; rr < 16; ++rr) {
        const int c = th + rr * 4;
        tile[c][tl] = f2bf(x[((size_t)b * CC + c0 + c) * NN + n0 + tl]);
    }
    __syncthreads();
    #pragma unroll
    for (int rr = 0; rr < 16; ++rr) {
        const int n = th + rr * 4;
        xbf[((size_t)b * NN + n0 + n) * CC + c0 + tl] = tile[tl][n];
    }
}

// ---------------------------------------------------------------------------
// Kernel 2: QKV projection as MFMA GEMM: [320 x 256] @ [256 x N].
// ---------------------------------------------------------------------------
__global__ __launch_bounds__(512) void qkv_gemm(
    const u16* __restrict__ Wb, const float* __restrict__ biasb,
    const u16* __restrict__ xbf,
    u16* __restrict__ qt, u16* __restrict__ kt, u16* __restrict__ v)
{
    const int b   = blockIdx.y;
    const int n0  = blockIdx.x * 64;
    const int t   = threadIdx.x;
    const int wid = t >> 6;
    const int mw  = wid & 3;
    const int nw  = wid >> 2;
    const int lane = t & 63;
    const int g    = lane >> 4;
    const int c16  = lane & 15;

    f32x4 acc[5][2];
    #pragma unroll
    for (int mf = 0; mf < 5; ++mf)
        #pragma unroll
        for (int nf = 0; nf < 2; ++nf)
            #pragma unroll
            for (int r = 0; r < 4; ++r) acc[mf][nf][r] = 0.f;

    const u16* xb = xbf + (size_t)b * NN * CC;

    #pragma unroll
    for (int kk = 0; kk < 8; ++kk) {
        bf16x8 xf[2];
        #pragma unroll
        for (int nf = 0; nf < 2; ++nf)
            xf[nf] = *(const bf16x8*)(xb + (size_t)(n0 + nw * 32 + nf * 16 + c16) * CC + kk * 32 + g * 8);
        #pragma unroll
        for (int mf = 0; mf < 5; ++mf) {
            const bf16x8 wf = *(const bf16x8*)(Wb + (size_t)(mw * 80 + mf * 16 + c16) * CC + kk * 32 + g * 8);
            #pragma unroll
            for (int nf = 0; nf < 2; ++nf)
                acc[mf][nf] = __builtin_amdgcn_mfma_f32_16x16x32_bf16(wf, xf[nf], acc[mf][nf], 0, 0, 0);
        }
    }

    #pragma unroll
    for (int mf = 0; mf < 5; ++mf) {
        #pragma unroll
        for (int nf = 0; nf < 2; ++nf) {
            const int n = n0 + nw * 32 + nf * 16 + c16;
            #pragma unroll
            for (int r = 0; r < 4; ++r) {
                const int row = mw * 80 + mf * 16 + g * 4 + r;
                const float val = acc[mf][nf][r] + biasb[row];
                if (row < DQK)
                    qt[((size_t)b * NN + n) * DQK + row] = f2bf(val);
                else if (row < 2 * DQK)
                    kt[((size_t)b * NN + n) * DQK + (row - DQK)] = f2bf(val);
                else
                    v[((size_t)b * CC + (row - 2 * DQK)) * NN + n] = f2bf(val);
            }
        }
    }
}

// ---------------------------------------------------------------------------
// Kernel 3: MFMA flash attention, 2-way KV split, K staged in LDS.
// 8 waves: waves 0-3 QK^T+softmax (16 q-rows each, K frags from LDS);
// all 8 waves PV (32 channels each, V inline from global/L2).
// K tile double-buffered in LDS, staged T14-style (early global load ->
// late ds_write before the barrier) by all 512 threads (16B each).
// Register budget: kb[8] (64 VGPR) eliminated so VGPR+AGPR <= 128 ->
// 4 waves/SIMD -> TWO 512-thread blocks per CU (R6 post-mortem: 116 VGPR
// + 32 AGPR = 148 > 128 kept the second block out; R5 showed <=128 total
// does co-reside at 45% occupancy).
// grid BB*NQB*NSPLIT (XCD-swizzled: xcd = 2b+s), block 512.
// ---------------------------------------------------------------------------
template<int NSPLIT>
__global__ __launch_bounds__(512, 2) void attn_kernel(
    const u16* __restrict__ qt, const u16* __restrict__ kt,
    const u16* __restrict__ vg, const float* __restrict__ x,
    const float* __restrict__ gamma_p, float* __restrict__ out,
    float* __restrict__ Opart, float* __restrict__ mlpart)
{
    const int id   = blockIdx.x;
    const int xcd  = id & 7;
    const int b    = xcd >> 1;
    int qb, s;
    if (NSPLIT == 2) { qb = id >> 3;                      s = xcd & 1; }
    else             { qb = ((xcd & 1) << 5) | (id >> 3); s = 0; }
    const int i0     = qb * QBLK;
    const int j0base = s * (NN / NSPLIT);
    const int ntiles = (NN / NSPLIT) / KVB;

    const int t    = threadIdx.x;
    const int wid  = t >> 6;        // 0..7
    const int lane = t & 63;
    const int g    = lane >> 4;
    const int c16  = lane & 15;

    __shared__ __align__(16) u16   P_s[2][QBLK * KVB];   // 2 x 16 KB, XOR-swizzled
    __shared__ __align__(16) u16   K_s[2][KVB * DQK];    // 2 x 8 KB, [jf][g][c16][8e]
    __shared__ float alpha_s[2][QBLK];
    __shared__ float l_s[QBLK];

    const bool qkw = (wid < 4);

    // Q A-fragment (QK waves): lane holds Q[q=i0+16w+c16][d=8g..8g+7]
    const bf16x8 qa = *(const bf16x8*)(qt + ((size_t)b * NN + i0 + (wid & 3) * 16 + c16) * DQK + g * 8);

    float m[4], l[4];
    #pragma unroll
    for (int r = 0; r < 4; ++r) { m[r] = -INFINITY; l[r] = 0.f; }

    f32x4 accv[2][4];   // [cf][qf]: channels wid*32+cf*16.., q cols qf*16..
    #pragma unroll
    for (int cf = 0; cf < 2; ++cf)
        #pragma unroll
        for (int qf = 0; qf < 4; ++qf)
            #pragma unroll
            for (int r = 0; r < 4; ++r) accv[cf][qf][r] = 0.f;

    const u16* ktb = kt + (size_t)b * NN * DQK;
    const u16* vb  = vg + (size_t)b * CC * NN + (size_t)(wid * 32) * NN;

    // staging geometry: thread t loads K[j0 + srow][sdbl*8 .. +8] (16B) into
    // LDS linear slot t*16B  (layout [jf=t>>6][g=(t>>4)&3][c16=t&15][8 elems])
    const int srow = ((t >> 6) << 4) | (t & 15);
    const int sdbl = (t >> 4) & 3;
    const u16* ksrc = ktb + (size_t)srow * DQK + sdbl * 8;   // + j0*DQK per tile

    // ---- prologue: stage K tile 0 into K_s[0]
    {
        const float4 kreg = *(const float4*)(ksrc + (size_t)j0base * DQK);
        *(float4*)&K_s[0][t * 8] = kreg;
    }
    __syncthreads();

    for (int jt = 0; jt < ntiles; ++jt) {
        const int j0  = j0base + jt * KVB;
        const int buf = jt & 1;

        // ---- early-issue: K tile jt+1 global load (lands under QK/softmax)
        const int jn = j0base + ((jt + 1) & (ntiles - 1)) * KVB;
        const float4 kreg = *(const float4*)(ksrc + (size_t)jn * DQK);

        if (qkw) {
            // ---- S = Q K^T (16 q x 128 j), K frags from LDS (conflict-free)
            f32x4 sres[8];
            #pragma unroll
            for (int jf = 0; jf < 8; ++jf) {
                const bf16x8 kf = *(const bf16x8*)&K_s[buf][jf * 512 + g * 128 + c16 * 8];
                sres[jf] = __builtin_amdgcn_mfma_f32_16x16x32_bf16(qa, kf, (f32x4){0.f, 0.f, 0.f, 0.f}, 0, 0, 0);
            }

            // ---- online softmax (rows r: q-local = 16*(wid&3) + 4g + r)
            float alpha[4];
            #pragma unroll
            for (int r = 0; r < 4; ++r) {
                float tm = sres[0][r];
                #pragma unroll
                for (int jf = 1; jf < 8; ++jf) tm = fmaxf(tm, sres[jf][r]);
                #pragma unroll
                for (int off = 8; off; off >>= 1) tm = fmaxf(tm, __shfl_xor(tm, off));
                const float mn = fmaxf(m[r], tm);
                alpha[r] = __expf(m[r] - mn);
                float ls = 0.f;
                #pragma unroll
                for (int jf = 0; jf < 8; ++jf) {
                    const float p = __expf(sres[jf][r] - mn);
                    sres[jf][r] = p;
                    ls += p;
                }
                #pragma unroll
                for (int off = 8; off; off >>= 1) ls += __shfl_xor(ls, off);
                l[r] = l[r] * alpha[r] + ls;
                m[r] = mn;
            }

            const int qbase = (wid & 3) * 16 + g * 4;
            if (c16 == 0) {
                #pragma unroll
                for (int r = 0; r < 4; ++r) alpha_s[buf][qbase + r] = alpha[r];
            }
            // P -> LDS bf16, swizzle: ushort idx ^= (row&15)<<3
            #pragma unroll
            for (int r = 0; r < 4; ++r) {
                const int row = qbase + r;
                const int swz = (row & 15) << 3;
                #pragma unroll
                for (int jf = 0; jf < 8; ++jf)
                    P_s[buf][(row * KVB + c16 + jf * 16) ^ swz] = f2bf(sres[jf][r]);
            }
        }

        // ---- late write: K tile jt+1 -> LDS (vmcnt wait covered by QK work)
        *(float4*)&K_s[buf ^ 1][t * 8] = kreg;

        __syncthreads();   // P_s[buf]/alpha_s[buf]/K_s[buf^1] ready

        // ---- rescale accumulators by alpha of their q-column
        float av[4];
        #pragma unroll
        for (int qf = 0; qf < 4; ++qf) av[qf] = alpha_s[buf][c16 + 16 * qf];
        #pragma unroll
        for (int cf = 0; cf < 2; ++cf)
            #pragma unroll
            for (int qf = 0; qf < 4; ++qf)
                #pragma unroll
                for (int r = 0; r < 4; ++r) accv[cf][qf][r] *= av[qf];

        // ---- PV: O^T[c][q] += V[c][j] * P[q][j]   (MFMA cluster, setprio)
        __builtin_amdgcn_s_setprio(1);
        #pragma unroll
        for (int ks = 0; ks < 4; ++ks) {
            #pragma unroll
            for (int qf = 0; qf < 4; ++qf) {
                const int row = c16 + 16 * qf;
                const int e   = (row * KVB + ks * 32 + g * 8) ^ ((row & 15) << 3);
                const bf16x8 pb = *(const bf16x8*)&P_s[buf][e];
                #pragma unroll
                for (int cf = 0; cf < 2; ++cf) {
                    const bf16x8 va = *(const bf16x8*)(vb + (size_t)(cf * 16 + c16) * NN + j0 + ks * 32 + g * 8);
                    accv[cf][qf] = __builtin_amdgcn_mfma_f32_16x16x32_bf16(va, pb, accv[cf][qf], 0, 0, 0);
                }
            }
        }
        __builtin_amdgcn_s_setprio(0);
    }

    if (NSPLIT == 2) {
        // ---- write unnormalized partial O + (m,l)
        if (qkw && c16 == 0) {
            float* mlp = mlpart + ((size_t)(b * NQB + qb) * 2 + s) * (2 * QBLK);
            #pragma unroll
            for (int r = 0; r < 4; ++r) {
                const int row = (wid & 3) * 16 + g * 4 + r;
                mlp[row]        = m[r];
                mlp[QBLK + row] = l[r];
            }
        }
        float* op = Opart + ((size_t)(b * NQB + qb) * 2 + s) * CC * QBLK;
        #pragma unroll
        for (int qf = 0; qf < 4; ++qf) {
            const int q = c16 + 16 * qf;
            #pragma unroll
            for (int cf = 0; cf < 2; ++cf) {
                #pragma unroll
                for (int r = 0; r < 4; ++r) {
                    const int c = wid * 32 + cf * 16 + g * 4 + r;
                    op[c * QBLK + q] = accv[cf][qf][r];
                }
            }
        }
    } else {
        // ---- direct epilogue: out = gamma * O/l + x
        if (qkw && c16 == 0) {
            #pragma unroll
            for (int r = 0; r < 4; ++r) l_s[(wid & 3) * 16 + g * 4 + r] = l[r];
        }
        __syncthreads();

        const float gam = gamma_p[0];
        #pragma unroll
        for (int qf = 0; qf < 4; ++qf) {
            const float linv = 1.0f / l_s[c16 + 16 * qf];
            const int   qcol = i0 + c16 + 16 * qf;
            #pragma unroll
            for (int cf = 0; cf < 2; ++cf) {
                #pragma unroll
                for (int r = 0; r < 4; ++r) {
                    const int    c = wid * 32 + cf * 16 + g * 4 + r;
                    const size_t o = ((size_t)b * CC + c) * NN + qcol;
                    out[o] = gam * (accv[cf][qf][r] * linv) + x[o];
                }
            }
        }
    }
}

// ---------------------------------------------------------------------------
// Kernel 4: merge the 2 KV-split partials -> final out (only when split).
// grid BB*NQB, block 256. Thread t: q = t&63, channel stripe t>>6.
// ---------------------------------------------------------------------------
__global__ __launch_bounds__(256) void merge_kernel(
    const float* __restrict__ Opart, const float* __restrict__ mlpart,
    const float* __restrict__ x, const float* __restrict__ gamma_p,
    float* __restrict__ out)
{
    const int bq = blockIdx.x;          // b*NQB + qb
    const int b  = bq >> 6;
    const int qb = bq & 63;
    const int t  = threadIdx.x;
    const int q  = t & 63;
    const int cw = t >> 6;

    const float* ml0 = mlpart + ((size_t)bq * 2 + 0) * (2 * QBLK);
    const float* ml1 = mlpart + ((size_t)bq * 2 + 1) * (2 * QBLK);
    const float m0 = ml0[q], l0 = ml0[QBLK + q];
    const float m1 = ml1[q], l1 = ml1[QBLK + q];
    const float M  = fmaxf(m0, m1);
    const float w0 = __expf(m0 - M), w1 = __expf(m1 - M);
    const float inv = 1.0f / (w0 * l0 + w1 * l1);
    const float gam = gamma_p[0];

    const float* o0 = Opart + ((size_t)bq * 2 + 0) * CC * QBLK;
    const float* o1 = Opart + ((size_t)bq * 2 + 1) * CC * QBLK;

    for (int c = cw; c < CC; c += 4) {
        const size_t xo = ((size_t)b * CC + c) * NN + qb * QBLK + q;
        out[xo] = gam * ((w0 * o0[c * QBLK + q] + w1 * o1[c * QBLK + q]) * inv) + x[xo];
    }
}

// ---------------------------------------------------------------------------
extern "C" void kernel_launch(void* const* d_in, const int* in_sizes, int n_in,
                              void* d_out, int out_size, void* d_ws, size_t ws_size,
                              hipStream_t stream)
{
    const float* x     = (const float*)d_in[0];
    const float* Wq    = (const float*)d_in[1];
    const float* bq    = (const float*)d_in[2];
    const float* Wk    = (const float*)d_in[3];
    const float* bk    = (const float*)d_in[4];
    const float* Wv    = (const float*)d_in[5];
    const float* bv    = (const float*)d_in[6];
    const float* gamma = (const float*)d_in[7];
    float* out = (float*)d_out;

    // workspace: Qt 1M | Kt 1M | V 8M | xbf 8M | Wb 160K | bias | Opart 33.5M | ml 256K
    u16* qt   = (u16*)d_ws;
    u16* kt   = qt  + (size_t)BB * NN * DQK;
    u16* v    = kt  + (size_t)BB * NN * DQK;
    u16* xbf  = v   + (size_t)BB * CC * NN;
    u16* Wb   = xbf + (size_t)BB * NN * CC;
    float* biasb  = (float*)(Wb + 320 * CC);
    float* Opart  = biasb + 320;
    float* mlpart = Opart + (size_t)BB * NQB * 2 * CC * QBLK;
    float* wsend  = mlpart + (size_t)BB * NQB * 2 * 2 * QBLK;
    const bool split = ((size_t)((char*)wsend - (char*)d_ws) <= ws_size);

    wprep_kernel<<<dim3(320), 256, 0, stream>>>(Wq, bq, Wk, bk, Wv, bv, Wb, biasb);
    xpose_kernel<<<dim3(NN / 64, CC / 64, BB), 256, 0, stream>>>(x, xbf);
    qkv_gemm<<<dim3(NN / 64, BB), 512, 0, stream>>>(Wb, biasb, xbf, qt, kt, v);

    if (split) {
        attn_kernel<2><<<dim3(BB * NQB * 2), 512, 0, stream>>>(qt, kt, v, x, gamma, out, Opart, mlpart);
        merge_kernel<<<dim3(BB * NQB), 256, 0, stream>>>(Opart, mlpart, x, gamma, out);
    } else {
        attn_kernel<1><<<dim3(BB * NQB), 512, 0, stream>>>(qt, kt, v, x, gamma, out, Opart, mlpart);
    }
}

// Round 8
// 132.497 us; speedup vs baseline: 1.2867x; 1.2867x over previous
//
#include <hip/hip_runtime.h>
#include <hip/hip_bf16.h>
#include <math.h>

#define BB   4
#define CC   256
#define DQK  32
#define NN   4096
#define QBLK 64
#define KVB  128
#define NQB  (NN / QBLK)
#define NTILES (NN / KVB)
#define KSPLIT 8
#define SCALE 0.17677669529663687f   // 1/sqrt(32 + 1e-8)

typedef short  bf16x8 __attribute__((ext_vector_type(8)));
typedef float  f32x4  __attribute__((ext_vector_type(4)));
typedef unsigned short u16;
typedef unsigned int   u32;

__device__ __forceinline__ u16 f2bf(float f) {
    __hip_bfloat16 h = __float2bfloat16(f);   // round-to-nearest
    return *reinterpret_cast<u16*>(&h);
}

// ---------------------------------------------------------------------------
// Kernel 0: pack W -> bf16 [320][256] (Q rows & bias scaled), bias -> f32[320]
// ---------------------------------------------------------------------------
__global__ __launch_bounds__(256) void wprep_kernel(
    const float* __restrict__ Wq, const float* __restrict__ bq,
    const float* __restrict__ Wk, const float* __restrict__ bk,
    const float* __restrict__ Wv, const float* __restrict__ bv,
    u16* __restrict__ Wb, float* __restrict__ biasb)
{
    const int r = blockIdx.x;
    const int t = threadIdx.x;
    float w, bias;
    if (r < DQK)          { w = Wq[r * CC + t] * SCALE;     bias = bq[r] * SCALE; }
    else if (r < 2 * DQK) { w = Wk[(r - DQK) * CC + t];     bias = bk[r - DQK];  }
    else                  { w = Wv[(r - 2 * DQK) * CC + t]; bias = bv[r - 2 * DQK]; }
    Wb[r * CC + t] = f2bf(w);
    if (t == 0) biasb[r] = bias;
}

// ---------------------------------------------------------------------------
// Kernel 1: transpose x [B][C][N] f32 -> xbf [B][N][C] bf16 (64x64 LDS tiles)
// ---------------------------------------------------------------------------
__global__ __launch_bounds__(256) void xpose_kernel(
    const float* __restrict__ x, u16* __restrict__ xbf)
{
    __shared__ u16 tile[64][65];
    const int b  = blockIdx.z;
    const int n0 = blockIdx.x * 64;
    const int c0 = blockIdx.y * 64;
    const int t  = threadIdx.x;
    const int tl = t & 63;
    const int th = t >> 6;

    #pragma unroll
    for (int rr = 0; rr < 16; ++rr) {
        const int c = th + rr * 4;
        tile[c][tl] = f2bf(x[((size_t)b * CC + c0 + c) * NN + n0 + tl]);
    }
    __syncthreads();
    #pragma unroll
    for (int rr = 0; rr < 16; ++rr) {
        const int n = th + rr * 4;
        xbf[((size_t)b * NN + n0 + n) * CC + c0 + tl] = tile[tl][n];
    }
}

// ---------------------------------------------------------------------------
// Kernel 2: QKV projection as MFMA GEMM: [320 x 256] @ [256 x N].
// ---------------------------------------------------------------------------
__global__ __launch_bounds__(512) void qkv_gemm(
    const u16* __restrict__ Wb, const float* __restrict__ biasb,
    const u16* __restrict__ xbf,
    u16* __restrict__ qt, u16* __restrict__ kt, u16* __restrict__ v)
{
    const int b   = blockIdx.y;
    const int n0  = blockIdx.x * 64;
    const int t   = threadIdx.x;
    const int wid = t >> 6;
    const int mw  = wid & 3;
    const int nw  = wid >> 2;
    const int lane = t & 63;
    const int g    = lane >> 4;
    const int c16  = lane & 15;

    f32x4 acc[5][2];
    #pragma unroll
    for (int mf = 0; mf < 5; ++mf)
        #pragma unroll
        for (int nf = 0; nf < 2; ++nf)
            #pragma unroll
            for (int r = 0; r < 4; ++r) acc[mf][nf][r] = 0.f;

    const u16* xb = xbf + (size_t)b * NN * CC;

    #pragma unroll
    for (int kk = 0; kk < 8; ++kk) {
        bf16x8 xf[2];
        #pragma unroll
        for (int nf = 0; nf < 2; ++nf)
            xf[nf] = *(const bf16x8*)(xb + (size_t)(n0 + nw * 32 + nf * 16 + c16) * CC + kk * 32 + g * 8);
        #pragma unroll
        for (int mf = 0; mf < 5; ++mf) {
            const bf16x8 wf = *(const bf16x8*)(Wb + (size_t)(mw * 80 + mf * 16 + c16) * CC + kk * 32 + g * 8);
            #pragma unroll
            for (int nf = 0; nf < 2; ++nf)
                acc[mf][nf] = __builtin_amdgcn_mfma_f32_16x16x32_bf16(wf, xf[nf], acc[mf][nf], 0, 0, 0);
        }
    }

    #pragma unroll
    for (int mf = 0; mf < 5; ++mf) {
        #pragma unroll
        for (int nf = 0; nf < 2; ++nf) {
            const int n = n0 + nw * 32 + nf * 16 + c16;
            #pragma unroll
            for (int r = 0; r < 4; ++r) {
                const int row = mw * 80 + mf * 16 + g * 4 + r;
                const float val = acc[mf][nf][r] + biasb[row];
                if (row < DQK)
                    qt[((size_t)b * NN + n) * DQK + row] = f2bf(val);
                else if (row < 2 * DQK)
                    kt[((size_t)b * NN + n) * DQK + (row - DQK)] = f2bf(val);
                else
                    v[((size_t)b * CC + (row - 2 * DQK)) * NN + n] = f2bf(val);
            }
        }
    }
}

// ---------------------------------------------------------------------------
// Kernel 3 (pass 1): softmax stats. Per block: 64 q-rows x (NN/KSPLIT) j.
// Swapped MFMA (A=K, B=Q) -> lane holds one q (c16) and 32 j values; row
// reduce = in-lane tree + 2 shfl_xor (g bits). Online (m,l) over 4 tiles.
// grid BB*NQB*KSPLIT = 2048, block 256 (4 waves, 16 q each).
// ---------------------------------------------------------------------------
__global__ __launch_bounds__(256) void stats_kernel(
    const u16* __restrict__ qt, const u16* __restrict__ kt,
    float* __restrict__ mlpart)
{
    const int id = blockIdx.x;
    const int ks = id & (KSPLIT - 1);
    const int rb = id >> 3;          // b*NQB + qb
    const int b  = rb >> 6;
    const int qb = rb & 63;
    const int i0 = qb * QBLK;

    const int t    = threadIdx.x;
    const int wid  = t >> 6;         // 0..3
    const int lane = t & 63;
    const int g    = lane >> 4;
    const int c16  = lane & 15;

    const u16* ktb = kt + (size_t)b * NN * DQK;
    // B-frag: Q[q = i0 + 16*wid + c16][d = 8g..+8]
    const bf16x8 qa = *(const bf16x8*)(qt + ((size_t)b * NN + i0 + wid * 16 + c16) * DQK + g * 8);

    float m = -INFINITY, l = 0.f;
    const int j0base = ks * (NN / KSPLIT);

    for (int jt = 0; jt < (NN / KSPLIT) / KVB; ++jt) {
        const int j0 = j0base + jt * KVB;
        f32x4 s[8];
        #pragma unroll
        for (int jf = 0; jf < 8; ++jf) {
            const bf16x8 kb = *(const bf16x8*)(ktb + (size_t)(j0 + jf * 16 + c16) * DQK + g * 8);
            s[jf] = __builtin_amdgcn_mfma_f32_16x16x32_bf16(kb, qa, (f32x4){0.f, 0.f, 0.f, 0.f}, 0, 0, 0);
        }
        // in-lane max over 32 (all same q), then across g groups
        float tm = -INFINITY;
        #pragma unroll
        for (int jf = 0; jf < 8; ++jf)
            #pragma unroll
            for (int r = 0; r < 4; ++r) tm = fmaxf(tm, s[jf][r]);
        tm = fmaxf(tm, __shfl_xor(tm, 16));
        tm = fmaxf(tm, __shfl_xor(tm, 32));
        const float mn = fmaxf(m, tm);
        float ls = 0.f;
        #pragma unroll
        for (int jf = 0; jf < 8; ++jf)
            #pragma unroll
            for (int r = 0; r < 4; ++r) ls += __expf(s[jf][r] - mn);
        ls += __shfl_xor(ls, 16);
        ls += __shfl_xor(ls, 32);
        l = l * __expf(m - mn) + ls;
        m = mn;
    }

    if (lane < 16) {    // g == 0 holds the full reduction
        float* mlp = mlpart + ((size_t)rb * KSPLIT + ks) * (2 * QBLK);
        mlp[wid * 16 + c16]        = m;
        mlp[QBLK + wid * 16 + c16] = l;
    }
}

// ---------------------------------------------------------------------------
// Kernel 4: merge KSPLIT stats partials -> m_g[b][n], invl_g[b][n].
// grid (B*NN)/256 = 64, block 256.
// ---------------------------------------------------------------------------
__global__ __launch_bounds__(256) void statsmerge_kernel(
    const float* __restrict__ mlpart,
    float* __restrict__ m_g, float* __restrict__ invl_g)
{
    const int row = blockIdx.x * 256 + threadIdx.x;   // b*NN + n
    const int b   = row >> 12;
    const int n   = row & (NN - 1);
    const int qb  = n >> 6;
    const int q   = n & 63;
    const float* base = mlpart + ((size_t)(b * NQB + qb) * KSPLIT) * (2 * QBLK);

    float m = -INFINITY;
    #pragma unroll
    for (int ks = 0; ks < KSPLIT; ++ks)
        m = fmaxf(m, base[ks * 2 * QBLK + q]);
    float l = 0.f;
    #pragma unroll
    for (int ks = 0; ks < KSPLIT; ++ks)
        l += base[ks * 2 * QBLK + QBLK + q] * __expf(base[ks * 2 * QBLK + q] - m);

    m_g[row]    = m;
    invl_g[row] = 1.0f / l;
}

// ---------------------------------------------------------------------------
// Kernel 5 (pass 2): GEMM-shaped attention. No online softmax: P = exp(S-m)
// elementwise with precomputed m; epilogue scales by invl. 8 waves: waves
// 0-3 QK^T (swapped: mfma(K,Q), lane-local q -> one m scalar, packed b64
// P-writes); ALL 8 waves PV (32 channels each). One barrier/tile, P double-
// buffered, K in registers prefetched 1 tile ahead, V prefetched at loop top.
// grid 256 (XCD-swizzled), block 512.
// ---------------------------------------------------------------------------
__global__ __launch_bounds__(512, 2) void attn_kernel(
    const u16* __restrict__ qt, const u16* __restrict__ kt,
    const u16* __restrict__ vg,
    const float* __restrict__ m_g, const float* __restrict__ invl_g,
    const float* __restrict__ x, const float* __restrict__ gamma_p,
    float* __restrict__ out)
{
    const int id   = blockIdx.x;
    const int xcd  = id & 7;
    const int b    = xcd >> 1;
    const int i0   = (((xcd & 1) << 5) + (id >> 3)) * QBLK;
    const int t    = threadIdx.x;
    const int wid  = t >> 6;        // 0..7
    const int lane = t & 63;
    const int g    = lane >> 4;
    const int c16  = lane & 15;

    __shared__ __align__(16) u16 P_s[2][QBLK * KVB];   // 2 x 16 KB, XOR-swizzled

    const bool qkw = (wid < 4);

    const u16* ktb = kt + (size_t)b * NN * DQK;
    const u16* vb  = vg + (size_t)b * CC * NN + (size_t)(wid * 32) * NN;

    // QK-wave constants: B-frag Q (q = i0+16*wid+c16), its m scalar, K tile 0
    bf16x8 qa;
    float  mq = 0.f;
    bf16x8 kb[8];
    if (qkw) {
        qa = *(const bf16x8*)(qt + ((size_t)b * NN + i0 + wid * 16 + c16) * DQK + g * 8);
        mq = m_g[(size_t)b * NN + i0 + wid * 16 + c16];
        #pragma unroll
        for (int jf = 0; jf < 8; ++jf)
            kb[jf] = *(const bf16x8*)(ktb + (size_t)(jf * 16 + c16) * DQK + g * 8);
    }

    f32x4 accv[2][4];   // [cf][qf]: channels wid*32+cf*16.., q cols qf*16..
    #pragma unroll
    for (int cf = 0; cf < 2; ++cf)
        #pragma unroll
        for (int qf = 0; qf < 4; ++qf)
            #pragma unroll
            for (int r = 0; r < 4; ++r) accv[cf][qf][r] = 0.f;

    for (int jt = 0; jt < NTILES; ++jt) {
        const int j0  = jt * KVB;
        const int buf = jt & 1;

        // ---- V prefetch for this tile (all waves): lands under QK phase
        bf16x8 va[2][4];
        #pragma unroll
        for (int cf = 0; cf < 2; ++cf)
            #pragma unroll
            for (int ksl = 0; ksl < 4; ++ksl)
                va[cf][ksl] = *(const bf16x8*)(vb + (size_t)(cf * 16 + c16) * NN + j0 + ksl * 32 + g * 8);

        if (qkw) {
            // ---- S^T = K Q^T (lane: q = i0+16wid+c16, j = jf*16+4g+r)
            f32x4 sres[8];
            #pragma unroll
            for (int jf = 0; jf < 8; ++jf)
                sres[jf] = __builtin_amdgcn_mfma_f32_16x16x32_bf16(kb[jf], qa, (f32x4){0.f, 0.f, 0.f, 0.f}, 0, 0, 0);

            // ---- prefetch next K tile (lands under exp/pack)
            const int jn = ((jt + 1) & (NTILES - 1)) * KVB;
            #pragma unroll
            for (int jf = 0; jf < 8; ++jf)
                kb[jf] = *(const bf16x8*)(ktb + (size_t)(jn + jf * 16 + c16) * DQK + g * 8);

            // ---- P = exp(S - m) -> bf16, packed 8B writes into swizzled LDS
            const int rowbase = (wid * 16 + c16) * KVB;
            const int swz     = c16 << 3;
            #pragma unroll
            for (int jf = 0; jf < 8; ++jf) {
                const float p0 = __expf(sres[jf][0] - mq);
                const float p1 = __expf(sres[jf][1] - mq);
                const float p2 = __expf(sres[jf][2] - mq);
                const float p3 = __expf(sres[jf][3] - mq);
                u32 lo = (u32)f2bf(p0) | ((u32)f2bf(p1) << 16);
                u32 hi = (u32)f2bf(p2) | ((u32)f2bf(p3) << 16);
                uint2 pk; pk.x = lo; pk.y = hi;
                *(uint2*)&P_s[buf][rowbase + ((jf * 16 + g * 4) ^ swz)] = pk;
            }
        }
        __syncthreads();   // P_s[buf] ready (also fences prev-tile PV reads of buf)

        // ---- PV: O^T[c][q] += V[c][j] * P[q][j]   (MFMA cluster, setprio)
        __builtin_amdgcn_s_setprio(1);
        #pragma unroll
        for (int ksl = 0; ksl < 4; ++ksl) {
            #pragma unroll
            for (int qf = 0; qf < 4; ++qf) {
                const int row = c16 + 16 * qf;
                const int e   = (row * KVB + ksl * 32 + g * 8) ^ ((row & 15) << 3);
                const bf16x8 pb = *(const bf16x8*)&P_s[buf][e];
                #pragma unroll
                for (int cf = 0; cf < 2; ++cf)
                    accv[cf][qf] = __builtin_amdgcn_mfma_f32_16x16x32_bf16(va[cf][ksl], pb, accv[cf][qf], 0, 0, 0);
            }
        }
        __builtin_amdgcn_s_setprio(0);
    }

    // ---- epilogue: out = gamma * O * invl + x   (no cross-wave sync needed)
    const float gam = gamma_p[0];
    #pragma unroll
    for (int qf = 0; qf < 4; ++qf) {
        const int   qcol = i0 + c16 + 16 * qf;
        const float linv = invl_g[(size_t)b * NN + qcol];
        #pragma unroll
        for (int cf = 0; cf < 2; ++cf) {
            #pragma unroll
            for (int r = 0; r < 4; ++r) {
                const int    c = wid * 32 + cf * 16 + g * 4 + r;
                const size_t o = ((size_t)b * CC + c) * NN + qcol;
                out[o] = gam * (accv[cf][qf][r] * linv) + x[o];
            }
        }
    }
}

// ---------------------------------------------------------------------------
extern "C" void kernel_launch(void* const* d_in, const int* in_sizes, int n_in,
                              void* d_out, int out_size, void* d_ws, size_t ws_size,
                              hipStream_t stream)
{
    const float* x     = (const float*)d_in[0];
    const float* Wq    = (const float*)d_in[1];
    const float* bq    = (const float*)d_in[2];
    const float* Wk    = (const float*)d_in[3];
    const float* bk    = (const float*)d_in[4];
    const float* Wv    = (const float*)d_in[5];
    const float* bv    = (const float*)d_in[6];
    const float* gamma = (const float*)d_in[7];
    float* out = (float*)d_out;

    // workspace: Qt 1M | Kt 1M | V 8M | xbf 8M | Wb 160K | biasb | mlpart 1M | m_g 64K | invl_g 64K
    u16* qt   = (u16*)d_ws;
    u16* kt   = qt  + (size_t)BB * NN * DQK;
    u16* v    = kt  + (size_t)BB * NN * DQK;
    u16* xbf  = v   + (size_t)BB * CC * NN;
    u16* Wb   = xbf + (size_t)BB * NN * CC;
    float* biasb  = (float*)(Wb + 320 * CC);
    float* mlpart = biasb + 320;
    float* m_g    = mlpart + (size_t)BB * NQB * KSPLIT * 2 * QBLK;
    float* invl_g = m_g + (size_t)BB * NN;

    wprep_kernel<<<dim3(320), 256, 0, stream>>>(Wq, bq, Wk, bk, Wv, bv, Wb, biasb);
    xpose_kernel<<<dim3(NN / 64, CC / 64, BB), 256, 0, stream>>>(x, xbf);
    qkv_gemm<<<dim3(NN / 64, BB), 512, 0, stream>>>(Wb, biasb, xbf, qt, kt, v);
    stats_kernel<<<dim3(BB * NQB * KSPLIT), 256, 0, stream>>>(qt, kt, mlpart);
    statsmerge_kernel<<<dim3((BB * NN) / 256), 256, 0, stream>>>(mlpart, m_g, invl_g);
    attn_kernel<<<dim3(BB * NQB), 512, 0, stream>>>(qt, kt, v, m_g, invl_g, x, gamma, out);
}